// Round 1
// baseline (76.482 us; speedup 1.0000x reference)
//
#include <hip/hip_runtime.h>

#define NN 128
#define HH 256
#define WW 256
#define CC 3

__global__ __launch_bounds__(256) void augment_kernel(
    const float* __restrict__ images,
    const int*   __restrict__ xflip_w,
    const float* __restrict__ xflip_gate,
    const int*   __restrict__ yflip_w,
    const float* __restrict__ yflip_gate,
    const int*   __restrict__ rot_w,
    const float* __restrict__ rot_gate,
    const float* __restrict__ trans_w,
    const float* __restrict__ trans_gate,
    float* __restrict__ out)
{
    const int row_id = blockIdx.x;      // n*HH + yo
    const int n  = row_id >> 8;         // HH = 256
    const int yo = row_id & 255;

    // ---- per-sample parameters (redundant per block; cached loads) ----
    const bool xf = (xflip_gate[n] < 1.0f) && (xflip_w[n] == 1);
    const bool yf = (yflip_gate[n] < 1.0f) && (yflip_w[n] == 1);
    const int  rw = (rot_gate[n] < 1.0f) ? rot_w[n] : 0;
    const bool fx_rot = (rw == 1) || (rw == 2);
    const bool fy_rot = (rw == 2) || (rw == 3);
    const bool tr     = (rw == 1) || (rw == 3);

    float tw0 = trans_w[n]      * 2.0f - 1.0f;   // x component
    float tw1 = trans_w[NN + n] * 2.0f - 1.0f;   // y component
    if (!(trans_gate[n] < 1.0f)) { tw0 = 0.0f; tw1 = 0.0f; }
    const int tx = (int)rintf(tw0 * (WW * 0.125f));  // round half-to-even, as jnp.round
    const int ty = (int)rintf(tw1 * (HH * 0.125f));

    // ---- reflected y source index for this output row ----
    int ym = (yo + ty) % (2 * HH - 2);
    if (ym < 0) ym += 2 * HH - 2;
    const int yi = HH - 1 - abs(HH - 1 - ym);

    const float* __restrict__ src = images + (size_t)n * (HH * WW * CC);
    float* __restrict__ dst = out + (size_t)row_id * (WW * CC);

    // 768 floats per row; 256 threads -> 3 strided iterations (coalesced stores)
    for (int e = threadIdx.x; e < WW * CC; e += 256) {
        const int xo = e / 3;
        const int c  = e - xo * 3;

        int xm = (xo - tx) % (2 * WW - 2);
        if (xm < 0) xm += 2 * WW - 2;
        int xi = WW - 1 - abs(WW - 1 - xm);

        int y = yi, x = xi;
        if (tr)     { const int t = y; y = x; x = t; }
        if (fy_rot) y = HH - 1 - y;
        if (fx_rot) x = WW - 1 - x;
        if (yf)     y = HH - 1 - y;
        if (xf)     x = WW - 1 - x;

        dst[e] = src[(y * WW + x) * CC + c];
    }
}

extern "C" void kernel_launch(void* const* d_in, const int* in_sizes, int n_in,
                              void* d_out, int out_size, void* d_ws, size_t ws_size,
                              hipStream_t stream)
{
    const float* images     = (const float*)d_in[0];
    const int*   xflip_w    = (const int*)  d_in[1];
    const float* xflip_gate = (const float*)d_in[2];
    const int*   yflip_w    = (const int*)  d_in[3];
    const float* yflip_gate = (const float*)d_in[4];
    const int*   rot_w      = (const int*)  d_in[5];
    const float* rot_gate   = (const float*)d_in[6];
    const float* trans_w    = (const float*)d_in[7];   // [2*N]
    const float* trans_gate = (const float*)d_in[8];   // [N]
    float* outp = (float*)d_out;

    dim3 grid(NN * HH);
    dim3 block(256);
    augment_kernel<<<grid, block, 0, stream>>>(images, xflip_w, xflip_gate,
                                               yflip_w, yflip_gate, rot_w, rot_gate,
                                               trans_w, trans_gate, outp);
}

// Round 2
// 41.757 us; speedup vs baseline: 1.8316x; 1.8316x over previous
//
#include <hip/hip_runtime.h>

#define NN 128
#define HH 256
#define WW 256
#define CC 3
#define HWC (HH * WW * CC)
#define TILE 32
#define LSTRIDE 99   // 99 % 32 == 3 -> lds addr % 32 = (3*i + 3*j + c) ~ 2-way max

__device__ __forceinline__ int reflect_idx(int v, int size) {
    int period = 2 * size - 2;
    int m = v % period;
    if (m < 0) m += period;
    return size - 1 - abs(size - 1 - m);
}

__global__ __launch_bounds__(256) void augment_kernel(
    const float* __restrict__ images,
    const int*   __restrict__ xflip_w,
    const float* __restrict__ xflip_gate,
    const int*   __restrict__ yflip_w,
    const float* __restrict__ yflip_gate,
    const int*   __restrict__ rot_w,
    const float* __restrict__ rot_gate,
    const float* __restrict__ trans_w,
    const float* __restrict__ trans_gate,
    float* __restrict__ out)
{
    __shared__ int   sy_arr[TILE];
    __shared__ int   sx_arr[TILE];
    __shared__ float tile[TILE * LSTRIDE];

    const int n       = blockIdx.x >> 6;        // 64 tiles per sample (8x8)
    const int tile_id = blockIdx.x & 63;
    const int yo0     = (tile_id >> 3) << 5;
    const int xo0     = (tile_id & 7) << 5;

    // ---- per-sample parameters (wave-uniform) ----
    const bool xf = (xflip_gate[n] < 1.0f) && (xflip_w[n] == 1);
    const bool yf = (yflip_gate[n] < 1.0f) && (yflip_w[n] == 1);
    const int  rw = (rot_gate[n] < 1.0f) ? rot_w[n] : 0;
    const bool fx = ((rw == 1) || (rw == 2)) ^ xf;
    const bool fy = ((rw == 2) || (rw == 3)) ^ yf;
    const bool tr = (rw == 1) || (rw == 3);

    float tw0 = trans_w[n]      * 2.0f - 1.0f;   // x component
    float tw1 = trans_w[NN + n] * 2.0f - 1.0f;   // y component
    if (!(trans_gate[n] < 1.0f)) { tw0 = 0.0f; tw1 = 0.0f; }
    const int tx = (int)rintf(tw0 * (WW * 0.125f));
    const int ty = (int)rintf(tw1 * (HH * 0.125f));

    // ---- per-tile separable source indices ----
    // tr=0: out(yo0+i, xo0+j) = src[ sy[i] ][ sx[j] ]
    // tr=1: out(yo0+i, xo0+j) = src[ sy[j] ][ sx[i] ]
    if (threadIdx.x < 64) {
        const int t = threadIdx.x & 31;
        if (threadIdx.x < 32) {
            int v = tr ? reflect_idx(xo0 + t - tx, WW)
                       : reflect_idx(yo0 + t + ty, HH);
            if (fy) v = HH - 1 - v;
            sy_arr[t] = v;
        } else {
            int v = tr ? reflect_idx(yo0 + t + ty, HH)
                       : reflect_idx(xo0 + t - tx, WW);
            if (fx) v = WW - 1 - v;
            sx_arr[t] = v;
        }
    }
    __syncthreads();

    const float* __restrict__ src = images + (size_t)n * HWC;

    if (!tr) {
        // direct path: loads & stores both row-contiguous
        for (int t = threadIdx.x; t < TILE * TILE * CC; t += 256) {
            const int i = t / 96;
            const int k = t - i * 96;        // j*3 + c
            const int j = k / 3;
            const int c = k - j * 3;
            const float v = src[(sy_arr[i] * WW + sx_arr[j]) * CC + c];
            out[((size_t)(n * HH + yo0 + i)) * (WW * CC) + xo0 * CC + k] = v;
        }
    } else {
        // transposed path: coalesced source-row loads -> LDS -> coalesced stores
        for (int t = threadIdx.x; t < TILE * TILE * CC; t += 256) {
            const int j = t / 96;            // output column index (source row sy[j])
            const int k = t - j * 96;        // i*3 + c
            const int i = k / 3;
            const int c = k - i * 3;
            tile[i * LSTRIDE + j * 3 + c] =
                src[(sy_arr[j] * WW + sx_arr[i]) * CC + c];
        }
        __syncthreads();
        for (int t = threadIdx.x; t < TILE * TILE * CC; t += 256) {
            const int i = t / 96;
            const int k = t - i * 96;        // j*3 + c
            out[((size_t)(n * HH + yo0 + i)) * (WW * CC) + xo0 * CC + k] =
                tile[i * LSTRIDE + k];
        }
    }
}

extern "C" void kernel_launch(void* const* d_in, const int* in_sizes, int n_in,
                              void* d_out, int out_size, void* d_ws, size_t ws_size,
                              hipStream_t stream)
{
    const float* images     = (const float*)d_in[0];
    const int*   xflip_w    = (const int*)  d_in[1];
    const float* xflip_gate = (const float*)d_in[2];
    const int*   yflip_w    = (const int*)  d_in[3];
    const float* yflip_gate = (const float*)d_in[4];
    const int*   rot_w      = (const int*)  d_in[5];
    const float* rot_gate   = (const float*)d_in[6];
    const float* trans_w    = (const float*)d_in[7];   // [2*N] flat
    const float* trans_gate = (const float*)d_in[8];   // [N] flat
    float* outp = (float*)d_out;

    dim3 grid(NN * 64);   // 8x8 tiles of 32x32 pixels per sample
    dim3 block(256);
    augment_kernel<<<grid, block, 0, stream>>>(images, xflip_w, xflip_gate,
                                               yflip_w, yflip_gate, rot_w, rot_gate,
                                               trans_w, trans_gate, outp);
}

// Round 3
// 38.108 us; speedup vs baseline: 2.0070x; 1.0958x over previous
//
#include <hip/hip_runtime.h>

#define NN 128
#define HH 256
#define WW 256
#define CC 3
#define HWC (HH * WW * CC)
#define TILE 32
#define LSTRIDE 100        // floats; 25 float4s per tile row, 16B aligned
#define ROWF (WW * CC)     // 768 floats per image row

__device__ __forceinline__ int reflect_idx(int v, int size) {
    int period = 2 * size - 2;
    int m = v % period;
    if (m < 0) m += period;
    return size - 1 - abs(size - 1 - m);
}

__global__ __launch_bounds__(256) void augment_kernel(
    const float* __restrict__ images,
    const int*   __restrict__ xflip_w,
    const float* __restrict__ xflip_gate,
    const int*   __restrict__ yflip_w,
    const float* __restrict__ yflip_gate,
    const int*   __restrict__ rot_w,
    const float* __restrict__ rot_gate,
    const float* __restrict__ trans_w,
    const float* __restrict__ trans_gate,
    float* __restrict__ out)
{
    __shared__ __align__(16) int   syv768[TILE];   // sy[i] * 768
    __shared__ __align__(16) int   sxc[96];        // sx[k/3]*3 + k%3
    __shared__ __align__(16) int   taddr[96];      // (k/3)*LSTRIDE + k%3  (tr path)
    __shared__ __align__(16) float tile[TILE * LSTRIDE];

    const int n       = blockIdx.x >> 6;        // 64 tiles per sample (8x8)
    const int tile_id = blockIdx.x & 63;
    const int yo0     = (tile_id >> 3) << 5;
    const int xo0     = (tile_id & 7) << 5;

    // ---- per-sample parameters (wave-uniform) ----
    const bool xf = (xflip_gate[n] < 1.0f) && (xflip_w[n] == 1);
    const bool yf = (yflip_gate[n] < 1.0f) && (yflip_w[n] == 1);
    const int  rw = (rot_gate[n] < 1.0f) ? rot_w[n] : 0;
    const bool fx = ((rw == 1) || (rw == 2)) ^ xf;
    const bool fy = ((rw == 2) || (rw == 3)) ^ yf;
    const bool tr = (rw == 1) || (rw == 3);

    float tw0 = trans_w[n]      * 2.0f - 1.0f;   // x component
    float tw1 = trans_w[NN + n] * 2.0f - 1.0f;   // y component
    if (!(trans_gate[n] < 1.0f)) { tw0 = 0.0f; tw1 = 0.0f; }
    const int tx = (int)rintf(tw0 * (WW * 0.125f));
    const int ty = (int)rintf(tw1 * (HH * 0.125f));

    // ---- per-block index tables ----
    // tr=0: out(i,j) = src[sy[i]][sx[j]] ; tr=1: out(i,j) = src[sy[j]][sx[i]]
    {
        const int t = threadIdx.x;
        if (t < TILE) {
            int v = tr ? reflect_idx(xo0 + t - tx, WW)
                       : reflect_idx(yo0 + t + ty, HH);
            if (fy) v = HH - 1 - v;
            syv768[t] = v * ROWF;
        } else if (t < 64) {
            const int u = t - 32;
            int v = tr ? reflect_idx(yo0 + u + ty, HH)
                       : reflect_idx(xo0 + u - tx, WW);
            if (fx) v = WW - 1 - v;
            // stash raw sx in sxc temporarily (expanded below)
            taddr[u] = v;                          // reuse as scratch
        }
    }
    __syncthreads();
    {
        const int t = threadIdx.x;
        if (t < 96) {
            const int j = t / 3, c = t - j * 3;
            sxc[t] = taddr[j] * 3 + c;             // read scratch sx
        }
    }
    __syncthreads();
    {
        const int t = threadIdx.x;
        if (t < 96) {
            const int j = t / 3, c = t - j * 3;
            taddr[t] = j * LSTRIDE + c;
        }
    }
    __syncthreads();

    const float* __restrict__ src = images + (size_t)n * HWC;
    const size_t outBase = (size_t)(n * HH + yo0) * ROWF + xo0 * CC; // floats, 384B aligned
    float4* __restrict__ out4 = (float4*)(out + outBase);
    const int4* sxc4 = (const int4*)sxc;
    const int4* ta4  = (const int4*)taddr;

    if (!tr) {
        // direct path: gather 12 floats into regs, then 3 float4 stores
        int   ib[3], qb[3];
        int4  off[3];
        float vals[12];
        #pragma unroll
        for (int v = 0; v < 3; ++v) {
            const int f = v * 256 + threadIdx.x;   // float4 index in [0,768)
            ib[v] = f / 24;
            qb[v] = f - ib[v] * 24;
            off[v] = sxc4[qb[v]];
        }
        #pragma unroll
        for (int v = 0; v < 3; ++v) {
            const int base = syv768[ib[v]];
            vals[v * 4 + 0] = src[base + off[v].x];
            vals[v * 4 + 1] = src[base + off[v].y];
            vals[v * 4 + 2] = src[base + off[v].z];
            vals[v * 4 + 3] = src[base + off[v].w];
        }
        #pragma unroll
        for (int v = 0; v < 3; ++v) {
            out4[ib[v] * (ROWF / 4) + qb[v]] =
                make_float4(vals[v * 4 + 0], vals[v * 4 + 1],
                            vals[v * 4 + 2], vals[v * 4 + 3]);
        }
    } else {
        // transposed path: coalesced source-row gathers -> LDS -> float4 out
        int   jb[3], qb[3];
        int4  off[3], tof[3];
        float vals[12];
        #pragma unroll
        for (int v = 0; v < 3; ++v) {
            const int f = v * 256 + threadIdx.x;
            jb[v] = f / 24;                        // source row group (= output col)
            qb[v] = f - jb[v] * 24;
            off[v] = sxc4[qb[v]];
            tof[v] = ta4[qb[v]];
        }
        #pragma unroll
        for (int v = 0; v < 3; ++v) {
            const int base = syv768[jb[v]];
            vals[v * 4 + 0] = src[base + off[v].x];
            vals[v * 4 + 1] = src[base + off[v].y];
            vals[v * 4 + 2] = src[base + off[v].z];
            vals[v * 4 + 3] = src[base + off[v].w];
        }
        #pragma unroll
        for (int v = 0; v < 3; ++v) {
            const int jc = jb[v] * 3;
            tile[tof[v].x + jc] = vals[v * 4 + 0];
            tile[tof[v].y + jc] = vals[v * 4 + 1];
            tile[tof[v].z + jc] = vals[v * 4 + 2];
            tile[tof[v].w + jc] = vals[v * 4 + 3];
        }
        __syncthreads();
        const float4* tile4 = (const float4*)tile;
        #pragma unroll
        for (int v = 0; v < 3; ++v) {
            const int f = v * 256 + threadIdx.x;
            const int i = f / 24;
            const int q = f - i * 24;
            out4[i * (ROWF / 4) + q] = tile4[i * (LSTRIDE / 4) + q];
        }
    }
}

extern "C" void kernel_launch(void* const* d_in, const int* in_sizes, int n_in,
                              void* d_out, int out_size, void* d_ws, size_t ws_size,
                              hipStream_t stream)
{
    const float* images     = (const float*)d_in[0];
    const int*   xflip_w    = (const int*)  d_in[1];
    const float* xflip_gate = (const float*)d_in[2];
    const int*   yflip_w    = (const int*)  d_in[3];
    const float* yflip_gate = (const float*)d_in[4];
    const int*   rot_w      = (const int*)  d_in[5];
    const float* rot_gate   = (const float*)d_in[6];
    const float* trans_w    = (const float*)d_in[7];   // [2*N] flat
    const float* trans_gate = (const float*)d_in[8];   // [N] flat
    float* outp = (float*)d_out;

    dim3 grid(NN * 64);   // 8x8 tiles of 32x32 pixels per sample
    dim3 block(256);
    augment_kernel<<<grid, block, 0, stream>>>(images, xflip_w, xflip_gate,
                                               yflip_w, yflip_gate, rot_w, rot_gate,
                                               trans_w, trans_gate, outp);
}